// Round 3
// baseline (490.234 us; speedup 1.0000x reference)
//
#include <hip/hip_runtime.h>
#include <math.h>

#define Bsz 2
#define Nn 2048
#define Dd 256
#define Hh 4
#define DHh 64
#define Jj 32
#define CE 274      // 2*EIN = 274
#define CEP 276     // padded to multiple of 4

__device__ __forceinline__ float4 ld4(const float* p) { return *reinterpret_cast<const float4*>(p); }

// ---------------------------------------------------------------------------
// K0: zero the coors_out region (atomics accumulate into it)
// ---------------------------------------------------------------------------
__global__ void k_zero(float* __restrict__ p, int n) {
    int i = blockIdx.x * 256 + threadIdx.x;
    if (i < n) p[i] = 0.f;
}

// ---------------------------------------------------------------------------
// K1: qkv = feats(4096x256) @ w_qkv(256x768) -> q,k,v each [b,h,n,64]
// grid (12, 64), block 256
// ---------------------------------------------------------------------------
__global__ __launch_bounds__(256) void k_qkv(const float* __restrict__ feats,
                                             const float* __restrict__ w,
                                             float* __restrict__ q,
                                             float* __restrict__ k,
                                             float* __restrict__ v) {
    __shared__ float As[32][68];
    __shared__ float Bs[32][68];
    const int t = threadIdx.x;
    const int bn = blockIdx.x * 64;   // col tile base (0..768)
    const int bm = blockIdx.y * 64;   // row tile base (0..4096)
    const int tn = t & 15, tm = t >> 4;
    const int ml = t >> 3, kl = (t & 7) << 2;
    const int kl2 = t >> 4, nl = (t & 15) << 2;
    float acc[4][4] = {};
    for (int k0 = 0; k0 < 256; k0 += 32) {
        float4 a0 = ld4(&feats[(size_t)(bm + ml) * 256 + k0 + kl]);
        float4 a1 = ld4(&feats[(size_t)(bm + ml + 32) * 256 + k0 + kl]);
        As[kl + 0][ml] = a0.x; As[kl + 1][ml] = a0.y; As[kl + 2][ml] = a0.z; As[kl + 3][ml] = a0.w;
        As[kl + 0][ml + 32] = a1.x; As[kl + 1][ml + 32] = a1.y; As[kl + 2][ml + 32] = a1.z; As[kl + 3][ml + 32] = a1.w;
        *reinterpret_cast<float4*>(&Bs[kl2][nl])      = ld4(&w[(size_t)(k0 + kl2) * 768 + bn + nl]);
        *reinterpret_cast<float4*>(&Bs[kl2 + 16][nl]) = ld4(&w[(size_t)(k0 + kl2 + 16) * 768 + bn + nl]);
        __syncthreads();
#pragma unroll
        for (int kk = 0; kk < 32; ++kk) {
            const float4 a = ld4(&As[kk][tm * 4]);
            const float4 bb = ld4(&Bs[kk][tn * 4]);
            const float av[4] = {a.x, a.y, a.z, a.w};
            const float bv[4] = {bb.x, bb.y, bb.z, bb.w};
#pragma unroll
            for (int mi = 0; mi < 4; ++mi)
#pragma unroll
                for (int ni = 0; ni < 4; ++ni) acc[mi][ni] += av[mi] * bv[ni];
        }
        __syncthreads();
    }
    const int sec = bn >> 8;
    const int h_ = (bn & 255) >> 6;
    float* dst = sec == 0 ? q : (sec == 1 ? k : v);
#pragma unroll
    for (int mi = 0; mi < 4; ++mi) {
        const int row = bm + tm * 4 + mi;
        const int b_ = row >> 11, n_ = row & 2047;
        float4 o = {acc[mi][0], acc[mi][1], acc[mi][2], acc[mi][3]};
        *reinterpret_cast<float4*>(&dst[(((size_t)b_ * Hh + h_) * Nn + n_) * DHh + tn * 4]) = o;
    }
}

// ---------------------------------------------------------------------------
// K2: qproj[bh,n,c] = q[bh,n,:] @ w_e1[0:64,:] + b_e1   (c padded to 276, pad=0)
//     kproj[bh,n,c] = k[bh,n,:] @ w_e1[64:128,:]
// grid (5, 32, 16=bh*2), block 256
// ---------------------------------------------------------------------------
__global__ __launch_bounds__(256) void k_proj(const float* __restrict__ q,
                                              const float* __restrict__ k,
                                              const float* __restrict__ w_e1,
                                              const float* __restrict__ b_e1,
                                              float* __restrict__ qproj,
                                              float* __restrict__ kproj) {
    __shared__ float As[32][68];
    __shared__ float Bs[32][68];
    const int t = threadIdx.x;
    const int z = blockIdx.z;
    const int which = z & 1;       // 0 = q, 1 = k
    const int bh = z >> 1;         // 0..7
    const float* src = which ? k : q;
    const float* wsl = w_e1 + (which ? 64 * CE : 0);
    float* dst = which ? kproj : qproj;
    const int c0 = blockIdx.x * 64;
    const int n0 = blockIdx.y * 64;
    const int tn = t & 15;   // n sub-tile
    const int tc = t >> 4;   // c sub-tile
    const int ml = t >> 3, kl = (t & 7) << 2;
    const int kl2 = t >> 4, nl = (t & 15) << 2;
    float acc[4][4] = {};    // [ni][ci]
    for (int k0 = 0; k0 < 64; k0 += 32) {
        float4 a0 = ld4(&src[((size_t)bh * Nn + n0 + ml) * 64 + k0 + kl]);
        float4 a1 = ld4(&src[((size_t)bh * Nn + n0 + ml + 32) * 64 + k0 + kl]);
        As[kl + 0][ml] = a0.x; As[kl + 1][ml] = a0.y; As[kl + 2][ml] = a0.z; As[kl + 3][ml] = a0.w;
        As[kl + 0][ml + 32] = a1.x; As[kl + 1][ml + 32] = a1.y; As[kl + 2][ml + 32] = a1.z; As[kl + 3][ml + 32] = a1.w;
#pragma unroll
        for (int e = 0; e < 4; ++e) {
            const int c = c0 + nl + e;
            Bs[kl2][nl + e]      = (c < CE) ? wsl[(size_t)(k0 + kl2) * CE + c] : 0.f;
            Bs[kl2 + 16][nl + e] = (c < CE) ? wsl[(size_t)(k0 + kl2 + 16) * CE + c] : 0.f;
        }
        __syncthreads();
#pragma unroll
        for (int kk = 0; kk < 32; ++kk) {
            const float4 a = ld4(&As[kk][tn * 4]);
            const float4 bb = ld4(&Bs[kk][tc * 4]);
            const float av[4] = {a.x, a.y, a.z, a.w};
            const float bv[4] = {bb.x, bb.y, bb.z, bb.w};
#pragma unroll
            for (int ni = 0; ni < 4; ++ni)
#pragma unroll
                for (int ci = 0; ci < 4; ++ci) acc[ni][ci] += av[ni] * bv[ci];
        }
        __syncthreads();
    }
    const int cbase = c0 + tc * 4;
    if (cbase < CEP) {
        float bias[4];
#pragma unroll
        for (int ci = 0; ci < 4; ++ci) {
            const int c = cbase + ci;
            bias[ci] = (!which && c < CE) ? b_e1[c] : 0.f;
        }
#pragma unroll
        for (int ni = 0; ni < 4; ++ni) {
            const int n = n0 + tn * 4 + ni;
            float4 o = {acc[ni][0] + bias[0], acc[ni][1] + bias[1],
                        acc[ni][2] + bias[2], acc[ni][3] + bias[3]};
            *reinterpret_cast<float4*>(&dst[(size_t)(bh * Nn + n) * CEP + cbase]) = o;
        }
    }
}

// ---------------------------------------------------------------------------
// K3 v2: edge kernel, head-PAIR blocks.
// block = (b, hp, 8 query nodes); 256 threads = 8 i x 32 j; each thread does
// one (i,j) edge for BOTH heads of the pair (rp / sincos shared).
// grid 1024 = B * 2 * (N/8).
// ---------------------------------------------------------------------------
__global__ __launch_bounds__(256, 4) void k_edge2(
    const float* __restrict__ coors, const int* __restrict__ nbhd,
    const float* __restrict__ qproj, const float* __restrict__ kproj,
    const float* __restrict__ v, const float* __restrict__ basis,
    const float* __restrict__ w_e1, const float* __restrict__ w_e2, const float* __restrict__ b_e2,
    const float* __restrict__ w_a1, const float* __restrict__ b_a1,
    const float* __restrict__ w_a2, const float* __restrict__ b_a2,
    const float* __restrict__ w_c1, const float* __restrict__ b_c1,
    const float* __restrict__ w_c2, const float* __restrict__ b_c2,
    float* __restrict__ out_tmp, float* __restrict__ coors_out) {

    __shared__ float s_we2[CEP][16];   // 17664 B (rows >= CE zeroed)
    __shared__ float s_we1r[9][CEP];   // 9936 B  (cols >= CE zeroed)
    __shared__ float s_wa1[1024];      // 4096 B
    __shared__ float s_wc1[1024];      // 4096 B
    __shared__ float s_wa2[64], s_wc2[64], s_ba1[64], s_bc1[64], s_be2[16];
    __shared__ float s_attn[2][8][33]; // 2112 B
    __shared__ int s_nbr[8][33];       // 1056 B   -> total ~40.0 KB

    const int t = threadIdx.x;
    const int blk = blockIdx.x;
    const int ichunk = blk & 255;      // N/8 = 256
    const int z = blk >> 8;            // 0..3
    const int hp = z & 1;              // head pair 0 -> h0,h1 ; 1 -> h2,h3
    const int b = z >> 1;
    const int j = t & 31;
    const int il = t >> 5;             // 0..7
    const int i = ichunk * 8 + il;
    const int bh0 = b * Hh + hp * 2;
    const int bh1 = bh0 + 1;

    // ---- stage weights ----
    for (int x = t; x < CEP * 16; x += 256) {
        const int c = x >> 4, mm = x & 15;
        s_we2[c][mm] = (c < CE) ? w_e2[c * 16 + mm] : 0.f;
    }
    for (int x = t; x < 9 * CEP; x += 256) {
        const int r = x / CEP, c = x - r * CEP;
        s_we1r[r][c] = (c < CE) ? w_e1[(128 + r) * CE + c] : 0.f;
    }
    for (int x = t; x < 1024; x += 256) {
        s_wa1[x] = w_a1[x];
        s_wc1[x] = w_c1[x];
    }
    if (t < 64) { s_wa2[t] = w_a2[t]; s_wc2[t] = w_c2[t]; s_ba1[t] = b_a1[t]; s_bc1[t] = b_c1[t]; }
    if (t < 16) s_be2[t] = b_e2[t];
    __syncthreads();

    // ---- per-edge setup: neighbor + fourier encoding (shared across the head pair) ----
    const int nb = nbhd[((size_t)b * Nn + i) * Jj + j];
    const float* cp = &coors[((size_t)b * Nn + i) * 3];
    const float* np = &coors[((size_t)b * Nn + nb) * 3];
    const float dx = cp[0] - np[0], dy = cp[1] - np[1], dz = cp[2] - np[2];
    const float d2 = dx * dx + dy * dy + dz * dz;
    float renc[9];
    {
        float s = 1.f;
#pragma unroll
        for (int f = 0; f < 4; ++f) {
            float sv, cv;
            sincosf(d2 * s, &sv, &cv);
            renc[f] = sv;
            renc[4 + f] = cv;
            s *= 0.5f;
        }
        renc[8] = d2;
    }

    const float* qr0 = qproj + (size_t)(bh0 * Nn + i) * CEP;
    const float* qr1 = qproj + (size_t)(bh1 * Nn + i) * CEP;
    const float* kr0 = kproj + (size_t)(bh0 * Nn + nb) * CEP;
    const float* kr1 = kproj + (size_t)(bh1 * Nn + nb) * CEP;

    // ---- main loop with register double-buffering of the 4 input streams ----
    float m0[16] = {}, m1[16] = {};
    float4 cq0 = ld4(qr0), cq1 = ld4(qr1), ck0 = ld4(kr0), ck1 = ld4(kr1);
    for (int c4 = 0; c4 < CEP; c4 += 4) {
        const int cn = (c4 + 4 < CEP) ? c4 + 4 : 0;   // wrap: dummy (discarded) on last iter
        const float4 nq0 = ld4(qr0 + cn);
        const float4 nq1 = ld4(qr1 + cn);
        const float4 nk0 = ld4(kr0 + cn);
        const float4 nk1 = ld4(kr1 + cn);

        float rx = 0.f, ry = 0.f, rz = 0.f, rw = 0.f;
#pragma unroll
        for (int r = 0; r < 9; ++r) {
            const float4 w = ld4(&s_we1r[r][c4]);
            const float e = renc[r];
            rx += e * w.x; ry += e * w.y; rz += e * w.z; rw += e * w.w;
        }
        float h0[4], h1[4];
        h0[0] = fmaxf(cq0.x + ck0.x + rx, 0.f);
        h0[1] = fmaxf(cq0.y + ck0.y + ry, 0.f);
        h0[2] = fmaxf(cq0.z + ck0.z + rz, 0.f);
        h0[3] = fmaxf(cq0.w + ck0.w + rw, 0.f);
        h1[0] = fmaxf(cq1.x + ck1.x + rx, 0.f);
        h1[1] = fmaxf(cq1.y + ck1.y + ry, 0.f);
        h1[2] = fmaxf(cq1.z + ck1.z + rz, 0.f);
        h1[3] = fmaxf(cq1.w + ck1.w + rw, 0.f);
#pragma unroll
        for (int cc = 0; cc < 4; ++cc) {
            const float4 w0 = ld4(&s_we2[c4 + cc][0]);
            const float4 w1 = ld4(&s_we2[c4 + cc][4]);
            const float4 w2 = ld4(&s_we2[c4 + cc][8]);
            const float4 w3 = ld4(&s_we2[c4 + cc][12]);
            const float a0 = h0[cc], a1 = h1[cc];
            m0[0] += a0 * w0.x; m0[1] += a0 * w0.y; m0[2] += a0 * w0.z; m0[3] += a0 * w0.w;
            m0[4] += a0 * w1.x; m0[5] += a0 * w1.y; m0[6] += a0 * w1.z; m0[7] += a0 * w1.w;
            m0[8] += a0 * w2.x; m0[9] += a0 * w2.y; m0[10] += a0 * w2.z; m0[11] += a0 * w2.w;
            m0[12] += a0 * w3.x; m0[13] += a0 * w3.y; m0[14] += a0 * w3.z; m0[15] += a0 * w3.w;
            m1[0] += a1 * w0.x; m1[1] += a1 * w0.y; m1[2] += a1 * w0.z; m1[3] += a1 * w0.w;
            m1[4] += a1 * w1.x; m1[5] += a1 * w1.y; m1[6] += a1 * w1.z; m1[7] += a1 * w1.w;
            m1[8] += a1 * w2.x; m1[9] += a1 * w2.y; m1[10] += a1 * w2.z; m1[11] += a1 * w2.w;
            m1[12] += a1 * w3.x; m1[13] += a1 * w3.y; m1[14] += a1 * w3.z; m1[15] += a1 * w3.w;
        }
        cq0 = nq0; cq1 = nq1; ck0 = nk0; ck1 = nk1;
    }
#pragma unroll
    for (int mm = 0; mm < 16; ++mm) {
        m0[mm] = fmaxf(m0[mm] + s_be2[mm], 0.f);
        m1[mm] = fmaxf(m1[mm] + s_be2[mm], 0.f);
    }

    // ---- a/c heads for both heads ----
    const float ba2v = b_a2[0], bc2v = b_c2[0];
    float sim0 = ba2v, sim1 = ba2v, cw0 = bc2v, cw1 = bc2v;
    for (int u4 = 0; u4 < 64; u4 += 4) {
        const float4 ba = ld4(&s_ba1[u4]);
        const float4 bc = ld4(&s_bc1[u4]);
        float4 ta0 = ba, ta1 = ba, tc0 = bc, tc1 = bc;
#pragma unroll
        for (int mm = 0; mm < 16; ++mm) {
            const float4 wa = ld4(&s_wa1[mm * 64 + u4]);
            const float4 wc = ld4(&s_wc1[mm * 64 + u4]);
            const float v0 = m0[mm], v1 = m1[mm];
            ta0.x += v0 * wa.x; ta0.y += v0 * wa.y; ta0.z += v0 * wa.z; ta0.w += v0 * wa.w;
            ta1.x += v1 * wa.x; ta1.y += v1 * wa.y; ta1.z += v1 * wa.z; ta1.w += v1 * wa.w;
            tc0.x += v0 * wc.x; tc0.y += v0 * wc.y; tc0.z += v0 * wc.z; tc0.w += v0 * wc.w;
            tc1.x += v1 * wc.x; tc1.y += v1 * wc.y; tc1.z += v1 * wc.z; tc1.w += v1 * wc.w;
        }
        const float4 a2 = ld4(&s_wa2[u4]);
        const float4 c2 = ld4(&s_wc2[u4]);
        sim0 += fmaxf(ta0.x, 0.f) * a2.x + fmaxf(ta0.y, 0.f) * a2.y +
                fmaxf(ta0.z, 0.f) * a2.z + fmaxf(ta0.w, 0.f) * a2.w;
        sim1 += fmaxf(ta1.x, 0.f) * a2.x + fmaxf(ta1.y, 0.f) * a2.y +
                fmaxf(ta1.z, 0.f) * a2.z + fmaxf(ta1.w, 0.f) * a2.w;
        cw0 += fmaxf(tc0.x, 0.f) * c2.x + fmaxf(tc0.y, 0.f) * c2.y +
               fmaxf(tc0.z, 0.f) * c2.z + fmaxf(tc0.w, 0.f) * c2.w;
        cw1 += fmaxf(tc1.x, 0.f) * c2.x + fmaxf(tc1.y, 0.f) * c2.y +
               fmaxf(tc1.z, 0.f) * c2.z + fmaxf(tc1.w, 0.f) * c2.w;
    }

    // ---- coors_out: sum over heads locally, reduce over j, atomic across head-pairs ----
    {
        const float cws = cw0 + cw1;
        const float* bp = basis + ((size_t)(b * Nn + i) * Nn + nb) * 3;
        float px = cws * bp[0], py = cws * bp[1], pz = cws * bp[2];
#pragma unroll
        for (int off = 16; off >= 1; off >>= 1) {
            px += __shfl_xor(px, off, 32);
            py += __shfl_xor(py, off, 32);
            pz += __shfl_xor(pz, off, 32);
        }
        if (j == 0) {
            float* co = &coors_out[((size_t)b * Nn + i) * 3];
            atomicAdd(&co[0], px);
            atomicAdd(&co[1], py);
            atomicAdd(&co[2], pz);
        }
    }

    // ---- softmax over j (32 lanes) per head ----
    {
        float mx0 = sim0, mx1 = sim1;
#pragma unroll
        for (int off = 16; off >= 1; off >>= 1) {
            mx0 = fmaxf(mx0, __shfl_xor(mx0, off, 32));
            mx1 = fmaxf(mx1, __shfl_xor(mx1, off, 32));
        }
        const float e0 = __expf(sim0 - mx0);
        const float e1 = __expf(sim1 - mx1);
        float sm0 = e0, sm1 = e1;
#pragma unroll
        for (int off = 16; off >= 1; off >>= 1) {
            sm0 += __shfl_xor(sm0, off, 32);
            sm1 += __shfl_xor(sm1, off, 32);
        }
        s_attn[0][il][j] = e0 / sm0;
        s_attn[1][il][j] = e1 / sm1;
        s_nbr[il][j] = nb;
    }
    __syncthreads();

    // ---- attn @ v_nb: 16 output rows (8 i x 2 h), 16 threads per row, 4 d's each ----
    const int r = t >> 4;            // 0..15
    const int il2 = r >> 1;
    const int hl = r & 1;
    const int d0 = (t & 15) << 2;
    const float* vb = v + (size_t)(bh0 + hl) * Nn * DHh;
    float4 acc = {0.f, 0.f, 0.f, 0.f};
#pragma unroll 4
    for (int jj = 0; jj < 32; ++jj) {
        const float a = s_attn[hl][il2][jj];
        const int nb2 = s_nbr[il2][jj];
        const float4 vv = ld4(vb + (size_t)nb2 * DHh + d0);
        acc.x += a * vv.x; acc.y += a * vv.y; acc.z += a * vv.z; acc.w += a * vv.w;
    }
    const int gi = ichunk * 8 + il2;
    const int h = hp * 2 + hl;
    float* op = out_tmp + ((size_t)(b * Nn + gi) * Hh + h) * DHh + d0;
    *reinterpret_cast<float4*>(op) = acc;
}

// ---------------------------------------------------------------------------
// K4: out = tmp(4096x256) @ w_out(256x256) + b_out
// grid (4, 64), block 256
// ---------------------------------------------------------------------------
__global__ __launch_bounds__(256) void k_out(const float* __restrict__ tmp,
                                             const float* __restrict__ w,
                                             const float* __restrict__ bias,
                                             float* __restrict__ outp) {
    __shared__ float As[32][68];
    __shared__ float Bs[32][68];
    const int t = threadIdx.x;
    const int bn = blockIdx.x * 64;
    const int bm = blockIdx.y * 64;
    const int tn = t & 15, tm = t >> 4;
    const int ml = t >> 3, kl = (t & 7) << 2;
    const int kl2 = t >> 4, nl = (t & 15) << 2;
    float acc[4][4] = {};
    for (int k0 = 0; k0 < 256; k0 += 32) {
        float4 a0 = ld4(&tmp[(size_t)(bm + ml) * 256 + k0 + kl]);
        float4 a1 = ld4(&tmp[(size_t)(bm + ml + 32) * 256 + k0 + kl]);
        As[kl + 0][ml] = a0.x; As[kl + 1][ml] = a0.y; As[kl + 2][ml] = a0.z; As[kl + 3][ml] = a0.w;
        As[kl + 0][ml + 32] = a1.x; As[kl + 1][ml + 32] = a1.y; As[kl + 2][ml + 32] = a1.z; As[kl + 3][ml + 32] = a1.w;
        *reinterpret_cast<float4*>(&Bs[kl2][nl])      = ld4(&w[(size_t)(k0 + kl2) * 256 + bn + nl]);
        *reinterpret_cast<float4*>(&Bs[kl2 + 16][nl]) = ld4(&w[(size_t)(k0 + kl2 + 16) * 256 + bn + nl]);
        __syncthreads();
#pragma unroll
        for (int kk = 0; kk < 32; ++kk) {
            const float4 a = ld4(&As[kk][tm * 4]);
            const float4 bb = ld4(&Bs[kk][tn * 4]);
            const float av[4] = {a.x, a.y, a.z, a.w};
            const float bv[4] = {bb.x, bb.y, bb.z, bb.w};
#pragma unroll
            for (int mi = 0; mi < 4; ++mi)
#pragma unroll
                for (int ni = 0; ni < 4; ++ni) acc[mi][ni] += av[mi] * bv[ni];
        }
        __syncthreads();
    }
    const int c = bn + tn * 4;
    const float4 bv4 = ld4(&bias[c]);
#pragma unroll
    for (int mi = 0; mi < 4; ++mi) {
        const int row = bm + tm * 4 + mi;
        float4 o = {acc[mi][0] + bv4.x, acc[mi][1] + bv4.y, acc[mi][2] + bv4.z, acc[mi][3] + bv4.w};
        *reinterpret_cast<float4*>(&outp[(size_t)row * 256 + c]) = o;
    }
}

// ---------------------------------------------------------------------------
extern "C" void kernel_launch(void* const* d_in, const int* in_sizes, int n_in,
                              void* d_out, int out_size, void* d_ws, size_t ws_size,
                              hipStream_t stream) {
    const float* feats = (const float*)d_in[0];
    const float* coors = (const float*)d_in[1];
    const float* basis = (const float*)d_in[2];
    const int* nbhd = (const int*)d_in[3];
    const float* w_qkv = (const float*)d_in[4];
    const float* w_out = (const float*)d_in[5];
    const float* b_out = (const float*)d_in[6];
    const float* w_e1 = (const float*)d_in[7];
    const float* b_e1 = (const float*)d_in[8];
    const float* w_e2 = (const float*)d_in[9];
    const float* b_e2 = (const float*)d_in[10];
    const float* w_a1 = (const float*)d_in[11];
    const float* b_a1 = (const float*)d_in[12];
    const float* w_a2 = (const float*)d_in[13];
    const float* b_a2 = (const float*)d_in[14];
    const float* w_c1 = (const float*)d_in[15];
    const float* b_c1 = (const float*)d_in[16];
    const float* w_c2 = (const float*)d_in[17];
    const float* b_c2 = (const float*)d_in[18];

    float* ws = (float*)d_ws;
    float* q = ws;                                     // 1,048,576
    float* k = q + (size_t)Bsz * Hh * Nn * DHh;        // 1,048,576
    float* v = k + (size_t)Bsz * Hh * Nn * DHh;        // 1,048,576
    float* qproj = v + (size_t)Bsz * Hh * Nn * DHh;    // 8*2048*276 = 4,521,984
    float* kproj = qproj + (size_t)Bsz * Hh * Nn * CEP;
    float* tmp = kproj + (size_t)Bsz * Hh * Nn * CEP;  // 1,048,576

    float* outp = (float*)d_out;
    float* coors_out = outp + (size_t)Bsz * Nn * Dd;

    hipLaunchKernelGGL(k_zero, dim3(48), dim3(256), 0, stream, coors_out, Bsz * Nn * 3);
    hipLaunchKernelGGL(k_qkv, dim3(12, 64), dim3(256), 0, stream, feats, w_qkv, q, k, v);
    hipLaunchKernelGGL(k_proj, dim3(5, 32, 16), dim3(256), 0, stream, q, k, w_e1, b_e1, qproj, kproj);
    hipLaunchKernelGGL(k_edge2, dim3(1024), dim3(256), 0, stream,
                       coors, nbhd, qproj, kproj, v, basis,
                       w_e1, w_e2, b_e2, w_a1, b_a1, w_a2, b_a2,
                       w_c1, b_c1, w_c2, b_c2, tmp, coors_out);
    hipLaunchKernelGGL(k_out, dim3(4, 64), dim3(256), 0, stream, tmp, w_out, b_out, outp);
}

// Round 5
// 314.872 us; speedup vs baseline: 1.5569x; 1.5569x over previous
//
#include <hip/hip_runtime.h>
#include <math.h>

#define Bsz 2
#define Nn 2048
#define Dd 256
#define Hh 4
#define DHh 64
#define Jj 32
#define CE 274      // 2*EIN = 274
#define CEP 288     // padded to multiple of 32 (9 MFMA K-steps)

typedef __attribute__((ext_vector_type(8))) short short8v;       // 8 bf16 (A/B frag)
typedef __attribute__((ext_vector_type(4))) float f32x4;         // C/D frag
typedef __attribute__((ext_vector_type(8))) unsigned short u16x8;

__device__ __forceinline__ float4 ld4(const float* p) { return *reinterpret_cast<const float4*>(p); }
__device__ __forceinline__ float bf2f(unsigned short u) {
    return __uint_as_float(((unsigned int)u) << 16);
}
__device__ __forceinline__ unsigned short f2bf(float f) {        // RNE
    unsigned int x = __float_as_uint(f);
    return (unsigned short)((x + 0x7fffu + ((x >> 16) & 1u)) >> 16);
}

// ---------------------------------------------------------------------------
// K1: qkv = feats(4096x256) @ w_qkv(256x768) -> q,k,v each [b,h,n,64] f32
// grid (12, 64), block 256
// ---------------------------------------------------------------------------
__global__ __launch_bounds__(256) void k_qkv(const float* __restrict__ feats,
                                             const float* __restrict__ w,
                                             float* __restrict__ q,
                                             float* __restrict__ k,
                                             float* __restrict__ v) {
    __shared__ float As[32][68];
    __shared__ float Bs[32][68];
    const int t = threadIdx.x;
    const int bn = blockIdx.x * 64;
    const int bm = blockIdx.y * 64;
    const int tn = t & 15, tm = t >> 4;
    const int ml = t >> 3, kl = (t & 7) << 2;
    const int kl2 = t >> 4, nl = (t & 15) << 2;
    float acc[4][4] = {};
    for (int k0 = 0; k0 < 256; k0 += 32) {
        float4 a0 = ld4(&feats[(size_t)(bm + ml) * 256 + k0 + kl]);
        float4 a1 = ld4(&feats[(size_t)(bm + ml + 32) * 256 + k0 + kl]);
        As[kl + 0][ml] = a0.x; As[kl + 1][ml] = a0.y; As[kl + 2][ml] = a0.z; As[kl + 3][ml] = a0.w;
        As[kl + 0][ml + 32] = a1.x; As[kl + 1][ml + 32] = a1.y; As[kl + 2][ml + 32] = a1.z; As[kl + 3][ml + 32] = a1.w;
        *reinterpret_cast<float4*>(&Bs[kl2][nl])      = ld4(&w[(size_t)(k0 + kl2) * 768 + bn + nl]);
        *reinterpret_cast<float4*>(&Bs[kl2 + 16][nl]) = ld4(&w[(size_t)(k0 + kl2 + 16) * 768 + bn + nl]);
        __syncthreads();
#pragma unroll
        for (int kk = 0; kk < 32; ++kk) {
            const float4 a = ld4(&As[kk][tm * 4]);
            const float4 bb = ld4(&Bs[kk][tn * 4]);
            const float av[4] = {a.x, a.y, a.z, a.w};
            const float bv[4] = {bb.x, bb.y, bb.z, bb.w};
#pragma unroll
            for (int mi = 0; mi < 4; ++mi)
#pragma unroll
                for (int ni = 0; ni < 4; ++ni) acc[mi][ni] += av[mi] * bv[ni];
        }
        __syncthreads();
    }
    const int sec = bn >> 8;
    const int h_ = (bn & 255) >> 6;
    float* dst = sec == 0 ? q : (sec == 1 ? k : v);
#pragma unroll
    for (int mi = 0; mi < 4; ++mi) {
        const int row = bm + tm * 4 + mi;
        const int b_ = row >> 11, n_ = row & 2047;
        float4 o = {acc[mi][0], acc[mi][1], acc[mi][2], acc[mi][3]};
        *reinterpret_cast<float4*>(&dst[(((size_t)b_ * Hh + h_) * Nn + n_) * DHh + tn * 4]) = o;
    }
}

// ---------------------------------------------------------------------------
// K2: qproj[bh,n,c] = bf16( q[bh,n,:] @ w_e1[0:64,:] + b_e1 )  (c pad 288, 0)
//     kproj[bh,n,c] = bf16( k[bh,n,:] @ w_e1[64:128,:] )
// grid (5, 32, 16=bh*2), block 256
// ---------------------------------------------------------------------------
__global__ __launch_bounds__(256) void k_proj(const float* __restrict__ q,
                                              const float* __restrict__ k,
                                              const float* __restrict__ w_e1,
                                              const float* __restrict__ b_e1,
                                              unsigned short* __restrict__ qproj,
                                              unsigned short* __restrict__ kproj) {
    __shared__ float As[32][68];
    __shared__ float Bs[32][68];
    const int t = threadIdx.x;
    const int z = blockIdx.z;
    const int which = z & 1;       // 0 = q, 1 = k
    const int bh = z >> 1;         // 0..7
    const float* src = which ? k : q;
    const float* wsl = w_e1 + (which ? 64 * CE : 0);
    unsigned short* dst = which ? kproj : qproj;
    const int c0 = blockIdx.x * 64;
    const int n0 = blockIdx.y * 64;
    const int tn = t & 15;   // n sub-tile
    const int tc = t >> 4;   // c sub-tile
    const int ml = t >> 3, kl = (t & 7) << 2;
    const int kl2 = t >> 4, nl = (t & 15) << 2;
    float acc[4][4] = {};    // [ni][ci]
    for (int k0 = 0; k0 < 64; k0 += 32) {
        float4 a0 = ld4(&src[((size_t)bh * Nn + n0 + ml) * 64 + k0 + kl]);
        float4 a1 = ld4(&src[((size_t)bh * Nn + n0 + ml + 32) * 64 + k0 + kl]);
        As[kl + 0][ml] = a0.x; As[kl + 1][ml] = a0.y; As[kl + 2][ml] = a0.z; As[kl + 3][ml] = a0.w;
        As[kl + 0][ml + 32] = a1.x; As[kl + 1][ml + 32] = a1.y; As[kl + 2][ml + 32] = a1.z; As[kl + 3][ml + 32] = a1.w;
#pragma unroll
        for (int e = 0; e < 4; ++e) {
            const int c = c0 + nl + e;
            Bs[kl2][nl + e]      = (c < CE) ? wsl[(size_t)(k0 + kl2) * CE + c] : 0.f;
            Bs[kl2 + 16][nl + e] = (c < CE) ? wsl[(size_t)(k0 + kl2 + 16) * CE + c] : 0.f;
        }
        __syncthreads();
#pragma unroll
        for (int kk = 0; kk < 32; ++kk) {
            const float4 a = ld4(&As[kk][tn * 4]);
            const float4 bb = ld4(&Bs[kk][tc * 4]);
            const float av[4] = {a.x, a.y, a.z, a.w};
            const float bv[4] = {bb.x, bb.y, bb.z, bb.w};
#pragma unroll
            for (int ni = 0; ni < 4; ++ni)
#pragma unroll
                for (int ci = 0; ci < 4; ++ci) acc[ni][ci] += av[ni] * bv[ci];
        }
        __syncthreads();
    }
    const int cbase = c0 + tc * 4;
    if (cbase < CEP) {
        float bias[4];
#pragma unroll
        for (int ci = 0; ci < 4; ++ci) {
            const int c = cbase + ci;
            bias[ci] = (!which && c < CE) ? b_e1[c] : 0.f;
        }
#pragma unroll
        for (int ni = 0; ni < 4; ++ni) {
            const int n = n0 + tn * 4 + ni;
            ushort4 o;
            o.x = f2bf(acc[ni][0] + bias[0]);
            o.y = f2bf(acc[ni][1] + bias[1]);
            o.z = f2bf(acc[ni][2] + bias[2]);
            o.w = f2bf(acc[ni][3] + bias[3]);
            *reinterpret_cast<ushort4*>(&dst[(size_t)(bh * Nn + n) * CEP + cbase]) = o;
        }
    }
}

// ---------------------------------------------------------------------------
// K3 v3: MFMA edge kernel. Wave = one (b,i), all 4 heads, 32 j's (2 M-tiles).
// Block = 4 waves = 4 i's. grid 1024 = B * N/4. No atomics.
// A/B frags both use k-mapping k=(lane>>4)*8+e (permutation-robust pairing).
// C/D (m89-verified): col=lane&15, row=(lane>>4)*4+reg.
// ---------------------------------------------------------------------------
__global__ __launch_bounds__(256, 4) void k_edge3(
    const float* __restrict__ coors, const int* __restrict__ nbhd,
    const unsigned short* __restrict__ qproj, const unsigned short* __restrict__ kproj,
    const float* __restrict__ v, const float* __restrict__ basis,
    const float* __restrict__ w_e1, const float* __restrict__ w_e2, const float* __restrict__ b_e2,
    const float* __restrict__ w_a1, const float* __restrict__ b_a1, const float* __restrict__ w_a2,
    const float* __restrict__ w_c1, const float* __restrict__ b_c1, const float* __restrict__ w_c2,
    const float* __restrict__ b_c2,
    float* __restrict__ out_tmp, float* __restrict__ coors_out) {

    __shared__ float s_we1r[9][CEP];               // 10368 B (cols >= CE zeroed)
    __shared__ unsigned short s_we2f[9 * 64 * 8];  // 9216 B: w_e2 B-frags per (kk,lane)
    __shared__ unsigned short s_wacf[2 * 4 * 64 * 8]; // 8192 B: w_a1^T/w_c1^T A-frags
    __shared__ float s_m[4][16][20];               // 5120 B: per-wave m roundtrip
    __shared__ float s_ba1[64], s_wa2[64], s_bc1[64], s_wc2[64]; // 1024 B
    __shared__ float s_attn[4][2][16];             // 512 B
    __shared__ int   s_nb[4][2][16];               // 512 B   -> ~34.9 KB

    const int t = threadIdx.x;
    const int blk0 = blockIdx.x;
    const int blk = (blk0 & 7) * 128 + (blk0 >> 3);   // XCD swizzle (1024 % 8 == 0)
    const int b = blk >> 9;            // 0..1
    const int ichunk = blk & 511;      // 0..511
    const int wid = t >> 6, lane = t & 63;
    const int lg = lane >> 4, lr = lane & 15;
    const int i = ichunk * 4 + wid;

    // ---- stage weights ----
    for (int x = t; x < 9 * CEP; x += 256) {
        const int r = x / CEP, c = x - r * CEP;
        s_we1r[r][c] = (c < CE) ? w_e1[(128 + r) * CE + c] : 0.f;
    }
    for (int x = t; x < 9 * 64 * 8; x += 256) {
        const int kk = x >> 9, rem = x & 511, ln = rem >> 3, e = rem & 7;
        const int c = kk * 32 + (ln >> 4) * 8 + e;
        s_we2f[x] = f2bf((c < CE) ? w_e2[c * 16 + (ln & 15)] : 0.f);
    }
    for (int x = t; x < 2 * 4 * 64 * 8; x += 256) {
        const int w01 = x >> 11, rem = x & 2047;
        const int ut = rem >> 9, ln = (rem >> 3) & 63, e = rem & 7;
        const int kidx = (ln >> 4) * 8 + e;
        const float val = (kidx < 16) ? (w01 ? w_c1 : w_a1)[kidx * 64 + ut * 16 + (ln & 15)] : 0.f;
        s_wacf[x] = f2bf(val);
    }
    if (t < 64) { s_ba1[t] = b_a1[t]; s_wa2[t] = w_a2[t]; s_bc1[t] = b_c1[t]; s_wc2[t] = w_c2[t]; }
    __syncthreads();

    const float be2v = b_e2[lr];
    const float bc2v = b_c2[0];

    const float cx = coors[((size_t)b * Nn + i) * 3 + 0];
    const float cy = coors[((size_t)b * Nn + i) * 3 + 1];
    const float cz = coors[((size_t)b * Nn + i) * 3 + 2];

    float sim[2][4], cw[2][4];
    float bas[2][3];

#pragma unroll
    for (int tt = 0; tt < 2; ++tt) {
        const int j = tt * 16 + lr;
        const int nb = nbhd[((size_t)b * Nn + i) * Jj + j];
        if (lg == 0) s_nb[wid][tt][lr] = nb;
        const float dx = cx - coors[((size_t)b * Nn + nb) * 3 + 0];
        const float dy = cy - coors[((size_t)b * Nn + nb) * 3 + 1];
        const float dz = cz - coors[((size_t)b * Nn + nb) * 3 + 2];
        const float d2 = dx * dx + dy * dy + dz * dz;
        bas[tt][0] = basis[((size_t)((size_t)b * Nn + i) * Nn + nb) * 3 + 0];
        bas[tt][1] = basis[((size_t)((size_t)b * Nn + i) * Nn + nb) * 3 + 1];
        bas[tt][2] = basis[((size_t)((size_t)b * Nn + i) * Nn + nb) * 3 + 2];

        float renc[9];
        {
            float s = 1.f;
#pragma unroll
            for (int f = 0; f < 4; ++f) {
                float sv, cv;
                sincosf(d2 * s, &sv, &cv);
                renc[f] = sv;
                renc[4 + f] = cv;
                s *= 0.5f;
            }
            renc[8] = d2;
        }

        const unsigned short* kpb = kproj + ((size_t)(b * Hh) * Nn + nb) * CEP;
        const unsigned short* qpb = qproj + ((size_t)(b * Hh) * Nn + i) * CEP;
        const size_t hstride = (size_t)Nn * CEP;

        f32x4 C0 = {0.f, 0.f, 0.f, 0.f};
        f32x4 C1 = {0.f, 0.f, 0.f, 0.f};
        f32x4 C2 = {0.f, 0.f, 0.f, 0.f};
        f32x4 C3 = {0.f, 0.f, 0.f, 0.f};

        for (int kk = 0; kk < 9; ++kk) {
            const int c0 = kk * 32 + lg * 8;
            // rp = renc @ w_e1r  (fp32, shared by all 4 heads)
            f32x4 rpa = {0.f, 0.f, 0.f, 0.f};
            f32x4 rpb = {0.f, 0.f, 0.f, 0.f};
#pragma unroll
            for (int r = 0; r < 9; ++r) {
                const f32x4 wa = *reinterpret_cast<const f32x4*>(&s_we1r[r][c0]);
                const f32x4 wb = *reinterpret_cast<const f32x4*>(&s_we1r[r][c0 + 4]);
                const float e = renc[r];
                rpa += e * wa;
                rpb += e * wb;
            }
            const short8v bfrag = *reinterpret_cast<const short8v*>(&s_we2f[(kk * 64 + lane) * 8]);
#pragma unroll
            for (int h = 0; h < 4; ++h) {
                const u16x8 kp8 = *reinterpret_cast<const u16x8*>(kpb + (size_t)h * hstride + c0);
                const u16x8 qp8 = *reinterpret_cast<const u16x8*>(qpb + (size_t)h * hstride + c0);
                short8v A;
#pragma unroll
                for (int e = 0; e < 8; ++e) {
                    const float rpv = (e < 4) ? rpa[e] : rpb[e - 4];
                    float hv = bf2f(qp8[e]) + bf2f(kp8[e]) + rpv;
                    hv = fmaxf(hv, 0.f);
                    A[e] = (short)f2bf(hv);
                }
                if (h == 0) C0 = __builtin_amdgcn_mfma_f32_16x16x32_bf16(A, bfrag, C0, 0, 0, 0);
                if (h == 1) C1 = __builtin_amdgcn_mfma_f32_16x16x32_bf16(A, bfrag, C1, 0, 0, 0);
                if (h == 2) C2 = __builtin_amdgcn_mfma_f32_16x16x32_bf16(A, bfrag, C2, 0, 0, 0);
                if (h == 3) C3 = __builtin_amdgcn_mfma_f32_16x16x32_bf16(A, bfrag, C3, 0, 0, 0);
            }
        }

        // per h: m roundtrip (LDS), a/c head GEMMs, sim/cw
#pragma unroll
        for (int h = 0; h < 4; ++h) {
            const f32x4 Ch = (h == 0) ? C0 : (h == 1) ? C1 : (h == 2) ? C2 : C3;
#pragma unroll
            for (int r = 0; r < 4; ++r)
                s_m[wid][lg * 4 + r][lr] = fmaxf(Ch[r] + be2v, 0.f);
            short8v Bm = {0, 0, 0, 0, 0, 0, 0, 0};
            if (lg < 2) {
                const f32x4 m0 = *reinterpret_cast<const f32x4*>(&s_m[wid][lr][lg * 8]);
                const f32x4 m1 = *reinterpret_cast<const f32x4*>(&s_m[wid][lr][lg * 8 + 4]);
                Bm[0] = (short)f2bf(m0[0]); Bm[1] = (short)f2bf(m0[1]);
                Bm[2] = (short)f2bf(m0[2]); Bm[3] = (short)f2bf(m0[3]);
                Bm[4] = (short)f2bf(m1[0]); Bm[5] = (short)f2bf(m1[1]);
                Bm[6] = (short)f2bf(m1[2]); Bm[7] = (short)f2bf(m1[3]);
            }
            float sa = 0.f, sc = 0.f;
#pragma unroll
            for (int ut = 0; ut < 4; ++ut) {
                const short8v fa = *reinterpret_cast<const short8v*>(&s_wacf[((0 * 4 + ut) * 64 + lane) * 8]);
                const short8v fc = *reinterpret_cast<const short8v*>(&s_wacf[((1 * 4 + ut) * 64 + lane) * 8]);
                f32x4 ca = *reinterpret_cast<const f32x4*>(&s_ba1[ut * 16 + lg * 4]);
                f32x4 cc = *reinterpret_cast<const f32x4*>(&s_bc1[ut * 16 + lg * 4]);
                ca = __builtin_amdgcn_mfma_f32_16x16x32_bf16(fa, Bm, ca, 0, 0, 0);
                cc = __builtin_amdgcn_mfma_f32_16x16x32_bf16(fc, Bm, cc, 0, 0, 0);
                const f32x4 w2a = *reinterpret_cast<const f32x4*>(&s_wa2[ut * 16 + lg * 4]);
                const f32x4 w2c = *reinterpret_cast<const f32x4*>(&s_wc2[ut * 16 + lg * 4]);
#pragma unroll
                for (int r = 0; r < 4; ++r) {
                    sa += fmaxf(ca[r], 0.f) * w2a[r];
                    sc += fmaxf(cc[r], 0.f) * w2c[r];
                }
            }
            sa += __shfl_xor(sa, 16); sa += __shfl_xor(sa, 32);
            sc += __shfl_xor(sc, 16); sc += __shfl_xor(sc, 32);
            sim[tt][h] = sa;
            cw[tt][h] = sc + bc2v;
        }
    }

    // ---- softmax + PV + coors (per head) ----
    float px = 0.f, py = 0.f, pz = 0.f;
#pragma unroll
    for (int h = 0; h < 4; ++h) {
        float mx = fmaxf(sim[0][h], sim[1][h]);
        mx = fmaxf(mx, __shfl_xor(mx, 8));
        mx = fmaxf(mx, __shfl_xor(mx, 4));
        mx = fmaxf(mx, __shfl_xor(mx, 2));
        mx = fmaxf(mx, __shfl_xor(mx, 1));
        const float e0 = __expf(sim[0][h] - mx);
        const float e1 = __expf(sim[1][h] - mx);
        float S = e0 + e1;
        S += __shfl_xor(S, 8); S += __shfl_xor(S, 4);
        S += __shfl_xor(S, 2); S += __shfl_xor(S, 1);
        const float inv = 1.f / S;
        if (lg == 0) { s_attn[wid][0][lr] = e0 * inv; s_attn[wid][1][lr] = e1 * inv; }

        px += cw[0][h] * bas[0][0] + cw[1][h] * bas[1][0];
        py += cw[0][h] * bas[0][1] + cw[1][h] * bas[1][1];
        pz += cw[0][h] * bas[0][2] + cw[1][h] * bas[1][2];

        const float* vb = v + (size_t)(b * Hh + h) * Nn * DHh;
        float4 acc = {0.f, 0.f, 0.f, 0.f};
#pragma unroll
        for (int jj = 0; jj < 8; ++jj) {
            const int j2 = lg * 8 + jj;
            const float a = s_attn[wid][j2 >> 4][j2 & 15];
            const int nb2 = s_nb[wid][j2 >> 4][j2 & 15];
            const float4 vv = ld4(vb + (size_t)nb2 * DHh + lr * 4);
            acc.x += a * vv.x; acc.y += a * vv.y; acc.z += a * vv.z; acc.w += a * vv.w;
        }
        acc.x += __shfl_xor(acc.x, 16); acc.x += __shfl_xor(acc.x, 32);
        acc.y += __shfl_xor(acc.y, 16); acc.y += __shfl_xor(acc.y, 32);
        acc.z += __shfl_xor(acc.z, 16); acc.z += __shfl_xor(acc.z, 32);
        acc.w += __shfl_xor(acc.w, 16); acc.w += __shfl_xor(acc.w, 32);
        if (lane < 16)
            *reinterpret_cast<float4*>(&out_tmp[(((size_t)b * Nn + i) * Hh + h) * DHh + lr * 4]) = acc;
    }
    px += __shfl_xor(px, 1); px += __shfl_xor(px, 2); px += __shfl_xor(px, 4); px += __shfl_xor(px, 8);
    py += __shfl_xor(py, 1); py += __shfl_xor(py, 2); py += __shfl_xor(py, 4); py += __shfl_xor(py, 8);
    pz += __shfl_xor(pz, 1); pz += __shfl_xor(pz, 2); pz += __shfl_xor(pz, 4); pz += __shfl_xor(pz, 8);
    if (lane == 0) {
        coors_out[((size_t)b * Nn + i) * 3 + 0] = px;
        coors_out[((size_t)b * Nn + i) * 3 + 1] = py;
        coors_out[((size_t)b * Nn + i) * 3 + 2] = pz;
    }
}

// ---------------------------------------------------------------------------
// K4: out = tmp(4096x256) @ w_out(256x256) + b_out
// grid (4, 64), block 256
// ---------------------------------------------------------------------------
__global__ __launch_bounds__(256) void k_out(const float* __restrict__ tmp,
                                             const float* __restrict__ w,
                                             const float* __restrict__ bias,
                                             float* __restrict__ outp) {
    __shared__ float As[32][68];
    __shared__ float Bs[32][68];
    const int t = threadIdx.x;
    const int bn = blockIdx.x * 64;
    const int bm = blockIdx.y * 64;
    const int tn = t & 15, tm = t >> 4;
    const int ml = t >> 3, kl = (t & 7) << 2;
    const int kl2 = t >> 4, nl = (t & 15) << 2;
    float acc[4][4] = {};
    for (int k0 = 0; k0 < 256; k0 += 32) {
        float4 a0 = ld4(&tmp[(size_t)(bm + ml) * 256 + k0 + kl]);
        float4 a1 = ld4(&tmp[(size_t)(bm + ml + 32) * 256 + k0 + kl]);
        As[kl + 0][ml] = a0.x; As[kl + 1][ml] = a0.y; As[kl + 2][ml] = a0.z; As[kl + 3][ml] = a0.w;
        As[kl + 0][ml + 32] = a1.x; As[kl + 1][ml + 32] = a1.y; As[kl + 2][ml + 32] = a1.z; As[kl + 3][ml + 32] = a1.w;
        *reinterpret_cast<float4*>(&Bs[kl2][nl])      = ld4(&w[(size_t)(k0 + kl2) * 256 + bn + nl]);
        *reinterpret_cast<float4*>(&Bs[kl2 + 16][nl]) = ld4(&w[(size_t)(k0 + kl2 + 16) * 256 + bn + nl]);
        __syncthreads();
#pragma unroll
        for (int kk = 0; kk < 32; ++kk) {
            const float4 a = ld4(&As[kk][tm * 4]);
            const float4 bb = ld4(&Bs[kk][tn * 4]);
            const float av[4] = {a.x, a.y, a.z, a.w};
            const float bv[4] = {bb.x, bb.y, bb.z, bb.w};
#pragma unroll
            for (int mi = 0; mi < 4; ++mi)
#pragma unroll
                for (int ni = 0; ni < 4; ++ni) acc[mi][ni] += av[mi] * bv[ni];
        }
        __syncthreads();
    }
    const int c = bn + tn * 4;
    const float4 bv4 = ld4(&bias[c]);
#pragma unroll
    for (int mi = 0; mi < 4; ++mi) {
        const int row = bm + tm * 4 + mi;
        float4 o = {acc[mi][0] + bv4.x, acc[mi][1] + bv4.y, acc[mi][2] + bv4.z, acc[mi][3] + bv4.w};
        *reinterpret_cast<float4*>(&outp[(size_t)row * 256 + c]) = o;
    }
}

// ---------------------------------------------------------------------------
extern "C" void kernel_launch(void* const* d_in, const int* in_sizes, int n_in,
                              void* d_out, int out_size, void* d_ws, size_t ws_size,
                              hipStream_t stream) {
    const float* feats = (const float*)d_in[0];
    const float* coors = (const float*)d_in[1];
    const float* basis = (const float*)d_in[2];
    const int* nbhd = (const int*)d_in[3];
    const float* w_qkv = (const float*)d_in[4];
    const float* w_out = (const float*)d_in[5];
    const float* b_out = (const float*)d_in[6];
    const float* w_e1 = (const float*)d_in[7];
    const float* b_e1 = (const float*)d_in[8];
    const float* w_e2 = (const float*)d_in[9];
    const float* b_e2 = (const float*)d_in[10];
    const float* w_a1 = (const float*)d_in[11];
    const float* b_a1 = (const float*)d_in[12];
    const float* w_a2 = (const float*)d_in[13];
    /* b_a2 (d_in[14]) unused: constant bias cancels in softmax */
    const float* w_c1 = (const float*)d_in[15];
    const float* b_c1 = (const float*)d_in[16];
    const float* w_c2 = (const float*)d_in[17];
    const float* b_c2 = (const float*)d_in[18];

    float* ws = (float*)d_ws;
    float* q = ws;                                        // 4 MB f32
    float* k = q + (size_t)Bsz * Hh * Nn * DHh;           // 4 MB f32
    float* v = k + (size_t)Bsz * Hh * Nn * DHh;           // 4 MB f32
    unsigned short* qproj = (unsigned short*)(v + (size_t)Bsz * Hh * Nn * DHh); // 9 MB bf16
    unsigned short* kproj = qproj + (size_t)Bsz * Hh * Nn * CEP;                // 9 MB bf16
    float* tmp = (float*)(kproj + (size_t)Bsz * Hh * Nn * CEP);                 // 4 MB f32

    float* outp = (float*)d_out;
    float* coors_out = outp + (size_t)Bsz * Nn * Dd;

    hipLaunchKernelGGL(k_qkv, dim3(12, 64), dim3(256), 0, stream, feats, w_qkv, q, k, v);
    hipLaunchKernelGGL(k_proj, dim3(5, 32, 16), dim3(256), 0, stream, q, k, w_e1, b_e1, qproj, kproj);
    hipLaunchKernelGGL(k_edge3, dim3(1024), dim3(256), 0, stream,
                       coors, nbhd, qproj, kproj, v, basis,
                       w_e1, w_e2, b_e2, w_a1, b_a1, w_a2,
                       w_c1, b_c1, w_c2, b_c2, tmp, coors_out);
    hipLaunchKernelGGL(k_out, dim3(4, 64), dim3(256), 0, stream, tmp, w_out, b_out, outp);
}